// Round 3
// baseline (1366.888 us; speedup 1.0000x reference)
//
#include <hip/hip_runtime.h>
#include <cstddef>

constexpr int V_CNT = 65536;
constexpr int E_CNT = 1048576;
constexpr int H_DIM = 128;
constexpr int CI = 34;   // chem in
constexpr int GI = 48;   // geom in
#define EPSF 1e-5f

typedef _Float16 f16;
typedef f16 f16x8 __attribute__((ext_vector_type(8)));
typedef float f32x4 __attribute__((ext_vector_type(4)));
#define MFMA16(a,b,c) __builtin_amdgcn_mfma_f32_16x16x32_f16(a,b,c,0,0,0)

__device__ __forceinline__ float sigmoidf_(float x){ return 1.0f/(1.0f+__expf(-x)); }
__device__ __forceinline__ float siluf_(float x){ return x/(1.0f+__expf(-x)); }
__device__ __forceinline__ float softplusf_(float x){
  return fmaxf(x,0.0f) + __logf(1.0f + __expf(-fabsf(x)));
}

// ---------------- prep: fold BN scale into all weights, convert to f16 col-major [col][k]
__global__ __launch_bounds__(256) void prep_kernel(
    const float* __restrict__ w1, const float* __restrict__ b1, const float* __restrict__ bn1,
    const float* __restrict__ w2, const float* __restrict__ b2, const float* __restrict__ bn2,
    const float* __restrict__ wg1, const float* __restrict__ bg1, const float* __restrict__ bng1,
    const float* __restrict__ wg2, const float* __restrict__ bg2, const float* __restrict__ bng2,
    const float* __restrict__ wf1, const float* __restrict__ bf1, const float* __restrict__ bnf1,
    const float* __restrict__ wf2, const float* __restrict__ bf2, const float* __restrict__ bnf2,
    f16* __restrict__ w1f, float* __restrict__ shift1,
    f16* __restrict__ w2f, float* __restrict__ shift2,
    f16* __restrict__ wg1f, float* __restrict__ shiftg1,
    f16* __restrict__ wg2f, float* __restrict__ shiftg2,
    f16* __restrict__ wf1f, float* __restrict__ shiftf1,
    f16* __restrict__ wf2f, float* __restrict__ shiftf2)
{
  int t = blockIdx.x*256 + threadIdx.x;
  if (t < 128*64){                       // chem L1: [128 cols][64 k], k>=34 zero
    int n = t>>6, k = t&63;
    float s = bn1[n]*rsqrtf(bn1[384+n]+EPSF);
    w1f[t] = (k<CI) ? (f16)(w1[k*128+n]*s) : (f16)0.f;
    if (k==0) shift1[n] = fmaf(s, b1[n]-bn1[256+n], bn1[128+n]);
  }
  if (t < 256*128){                      // chem L2: [256 cols][128 k]
    int n = t>>7, k = t&127;
    float s = bn2[n]*rsqrtf(bn2[768+n]+EPSF);
    w2f[t] = (f16)(w2[k*256+n]*s);
    if (k==0) shift2[n] = fmaf(s, b2[n]-bn2[512+n], bn2[256+n]);
  }
  if (t < 64*64){                        // geom L1: [64 cols][64 k], k>=48 zero
    int n = t>>6, k = t&63;
    float s = bng1[n]*rsqrtf(bng1[192+n]+EPSF);
    wg1f[t] = (k<GI) ? (f16)(wg1[k*64+n]*s) : (f16)0.f;
    if (k==0) shiftg1[n] = fmaf(s, bg1[n]-bng1[128+n], bng1[64+n]);
  }
  if (t < 64*64){                        // geom L2: [64 cols][64 k]
    int n = t>>6, k = t&63;
    float s = bng2[n]*rsqrtf(bng2[192+n]+EPSF);
    wg2f[t] = (f16)(wg2[k*64+n]*s);
    if (k==0) shiftg2[n] = fmaf(s, bg2[n]-bng2[128+n], bng2[64+n]);
  }
  if (t < 128*192){                      // feat L1: [128 cols][192 k]
    int n = t/192, k = t - n*192;
    float s = bnf1[n]*rsqrtf(bnf1[384+n]+EPSF);
    wf1f[t] = (f16)(wf1[k*128+n]*s);
    if (k==0) shiftf1[n] = fmaf(s, bf1[n]-bnf1[256+n], bnf1[128+n]);
  }
  if (t < 128*128){                      // feat L2: [128 cols][128 k]
    int n = t>>7, k = t&127;
    float s = bnf2[n]*rsqrtf(bnf2[384+n]+EPSF);
    wf2f[t] = (f16)(wf2[k*128+n]*s);
    if (k==0) shiftf2[n] = fmaf(s, bf2[n]-bnf2[256+n], bnf2[128+n]);
  }
}

// ---------------- counting sort of edges by vertex
__global__ __launch_bounds__(256) void hist_kernel(const int* __restrict__ vids, int* __restrict__ counts){
  int i = blockIdx.x*blockDim.x + threadIdx.x;
  int stride = gridDim.x*blockDim.x;
  for(; i<E_CNT; i+=stride) atomicAdd(&counts[vids[i]], 1);
}

__global__ __launch_bounds__(1024) void scan_kernel(const int* __restrict__ counts,
                                                    int* __restrict__ offsets,
                                                    int* __restrict__ offsets_work){
  __shared__ int ps[1024];
  const int t = threadIdx.x;
  int4 c[16]; int s = 0;
  const int4* cp = (const int4*)counts + (size_t)t*16;
  #pragma unroll
  for(int i=0;i<16;i++){ c[i]=cp[i]; s += c[i].x+c[i].y+c[i].z+c[i].w; }
  ps[t]=s; __syncthreads();
  for(int d=1; d<1024; d<<=1){
    int v = (t>=d) ? ps[t-d] : 0;
    __syncthreads();
    ps[t] += v;
    __syncthreads();
  }
  int run = ps[t]-s;     // exclusive prefix of this thread's 64-chunk
  int4* o1 = (int4*)offsets + (size_t)t*16;
  int4* o2 = (int4*)offsets_work + (size_t)t*16;
  #pragma unroll
  for(int i=0;i<16;i++){
    int4 cc=c[i]; int4 o;
    o.x=run; run+=cc.x; o.y=run; run+=cc.y; o.z=run; run+=cc.z; o.w=run; run+=cc.w;
    o1[i]=o; o2[i]=o;
  }
  if(t==1023) offsets[65536] = run;
}

__global__ __launch_bounds__(256) void scatter_kernel(const int* __restrict__ vids,
                                                      int* __restrict__ offsets_work,
                                                      int* __restrict__ perm){
  int i = blockIdx.x*blockDim.x + threadIdx.x;
  int stride = gridDim.x*blockDim.x;
  for(; i<E_CNT; i+=stride){
    int v = vids[i];
    int pos = atomicAdd(&offsets_work[v], 1);
    perm[pos] = i;
  }
}

// ---------------- geom MLP via MFMA: 64 vertices/block -> h_geom [V,64] f16
__global__ __launch_bounds__(256) void geom_mfma(
    const float* __restrict__ geom,
    const f16* __restrict__ wg1f, const float* __restrict__ shg1,
    const f16* __restrict__ wg2f, const float* __restrict__ shg2,
    f16* __restrict__ h_geom)
{
  __shared__ f16 Ag[64][72];   // row 144B (+4 bank stagger)
  const int t = threadIdx.x, w = t>>6, lane = t&63, n16 = lane&15, quad = lane>>4;
  const int v0 = blockIdx.x*64;
  const int col = w*16 + n16;

  for(int i=t;i<64*GI;i+=256){ int r=i/GI, k=i-r*GI; Ag[r][k] = (f16)geom[(size_t)v0*GI + i]; }
  { uint* Aw=(uint*)Ag; for(int i=t;i<64*8;i+=256){ int r=i>>3; Aw[r*36+24+(i&7)]=0u; } }

  f16x8 bg1[2], bg2[2];
  #pragma unroll
  for(int ks=0;ks<2;ks++){
    bg1[ks] = *(const f16x8*)(wg1f + (size_t)col*64 + ks*32 + quad*8);
    bg2[ks] = *(const f16x8*)(wg2f + (size_t)col*64 + ks*32 + quad*8);
  }
  __syncthreads();

  f32x4 c1[4];
  #pragma unroll
  for(int mt=0;mt<4;mt++) c1[mt] = (f32x4)(0.f);
  #pragma unroll
  for(int mt=0;mt<4;mt++)
    #pragma unroll
    for(int ks=0;ks<2;ks++){
      f16x8 a = *(const f16x8*)(&Ag[mt*16+n16][ks*32+quad*8]);
      c1[mt] = MFMA16(a, bg1[ks], c1[mt]);
    }
  __syncthreads();   // all layer-1 reads done before overwriting Ag

  float s1 = shg1[col];
  #pragma unroll
  for(int mt=0;mt<4;mt++)
    #pragma unroll
    for(int r=0;r<4;r++)
      Ag[mt*16+quad*4+r][col] = (f16)siluf_(c1[mt][r] + s1);
  __syncthreads();

  f32x4 c2[4];
  #pragma unroll
  for(int mt=0;mt<4;mt++) c2[mt] = (f32x4)(0.f);
  #pragma unroll
  for(int mt=0;mt<4;mt++)
    #pragma unroll
    for(int ks=0;ks<2;ks++){
      f16x8 a = *(const f16x8*)(&Ag[mt*16+n16][ks*32+quad*8]);
      c2[mt] = MFMA16(a, bg2[ks], c2[mt]);
    }
  float s2 = shg2[col];
  #pragma unroll
  for(int mt=0;mt<4;mt++)
    #pragma unroll
    for(int r=0;r<4;r++)
      h_geom[(size_t)(v0 + mt*16+quad*4+r)*64 + col] = (f16)(c2[mt][r] + s2);
}

// ---------------- chem MLP over sorted edges + LDS accumulate; 16 vertices/block
__global__ __launch_bounds__(256) void chem_gather(
    const float* __restrict__ chem, const int* __restrict__ perm,
    const int* __restrict__ offsets,
    const f16* __restrict__ w1f, const float* __restrict__ shift1,
    const f16* __restrict__ w2f, const float* __restrict__ shift2,
    float* __restrict__ h_chem)
{
  __shared__ f16 A1[64][72];     // 9216 B
  __shared__ f16 A2[64][136];    // 17408 B
  __shared__ float accs[16][128];// 8192 B
  __shared__ int loff[17];
  __shared__ int eidx[64];
  __shared__ __align__(16) int vloc[64];

  const int t = threadIdx.x, w = t>>6, lane = t&63, n16 = lane&15, quad = lane>>4;
  const int v0 = blockIdx.x*16;

  if(t<17) loff[t] = offsets[v0+t];
  for(int i=t;i<16*128;i+=256) ((float*)accs)[i] = 0.f;

  // hoist B fragments (L2-resident)
  const int ntab[4] = {2*w, 2*w+1, 2*w+8, 2*w+9};
  f16x8 b2[4][4];
  #pragma unroll
  for(int p=0;p<4;p++){
    int col = ntab[p]*16 + n16;
    #pragma unroll
    for(int ks=0;ks<4;ks++)
      b2[p][ks] = *(const f16x8*)(w2f + (size_t)col*128 + ks*32 + quad*8);
  }
  f16x8 b1[2][2];
  #pragma unroll
  for(int p=0;p<2;p++){
    int col = (2*w+p)*16 + n16;
    #pragma unroll
    for(int ks=0;ks<2;ks++)
      b1[p][ks] = *(const f16x8*)(w1f + (size_t)col*64 + ks*32 + quad*8);
  }
  float sh1v[2], shf[2], shc[2];
  __syncthreads();

  sh1v[0] = shift1[(2*w+0)*16 + n16];
  sh1v[1] = shift1[(2*w+1)*16 + n16];
  shf[0] = shift2[(2*w+0)*16 + n16];
  shf[1] = shift2[(2*w+1)*16 + n16];
  shc[0] = shift2[128 + (2*w+0)*16 + n16];
  shc[1] = shift2[128 + (2*w+1)*16 + n16];

  const int base = loff[0];
  const int nE = loff[16] - base;

  for(int tile=0; tile*64 < nE; ++tile){
    __syncthreads();                       // prev iter fully consumed vloc/A2
    if(t<64){
      int p = base + tile*64 + t;
      if(p < base + nE){
        eidx[t] = perm[p];
        int vl = 0;
        #pragma unroll
        for(int j=1;j<16;j++) vl += (p >= loff[j]) ? 1 : 0;
        vloc[t] = vl;
      } else { eidx[t] = -1; vloc[t] = -1; }
    }
    __syncthreads();
    { // stage A1 (gathered rows), zero pad k 34..63 (uint words 17..35 of 36/row)
      uint* A1w = (uint*)A1;
      for(int i=t;i<64*19;i+=256){ int r=i/19, wd=17+(i-r*19); A1w[r*36+wd]=0u; }
      for(int i=t;i<64*CI;i+=256){
        int e=i/CI, k=i-e*CI; int ed = eidx[e];
        A1[e][k] = (ed>=0) ? (f16)chem[(size_t)ed*CI + k] : (f16)0.f;
      }
    }
    __syncthreads();

    // layer 1
    f32x4 c1[4][2];
    #pragma unroll
    for(int mt=0;mt<4;mt++){ c1[mt][0]=(f32x4)(0.f); c1[mt][1]=(f32x4)(0.f); }
    #pragma unroll
    for(int mt=0;mt<4;mt++)
      #pragma unroll
      for(int ks=0;ks<2;ks++){
        f16x8 a = *(const f16x8*)(&A1[mt*16+n16][ks*32+quad*8]);
        #pragma unroll
        for(int p=0;p<2;p++) c1[mt][p] = MFMA16(a, b1[p][ks], c1[mt][p]);
      }
    #pragma unroll
    for(int mt=0;mt<4;mt++)
      #pragma unroll
      for(int p=0;p<2;p++){
        int col = (2*w+p)*16 + n16;
        #pragma unroll
        for(int r=0;r<4;r++)
          A2[mt*16+quad*4+r][col] = (f16)siluf_(c1[mt][p][r] + sh1v[p]);
      }
    __syncthreads();

    // layer 2
    f32x4 c2[4][4];
    #pragma unroll
    for(int mt=0;mt<4;mt++)
      #pragma unroll
      for(int p=0;p<4;p++) c2[mt][p] = (f32x4)(0.f);
    #pragma unroll
    for(int ks=0;ks<4;ks++){
      f16x8 a[4];
      #pragma unroll
      for(int mt=0;mt<4;mt++)
        a[mt] = *(const f16x8*)(&A2[mt*16+n16][ks*32+quad*8]);
      #pragma unroll
      for(int mt=0;mt<4;mt++)
        #pragma unroll
        for(int p=0;p<4;p++)
          c2[mt][p] = MFMA16(a[mt], b2[p][ks], c2[mt][p]);
    }

    // gate + LDS accumulate
    #pragma unroll
    for(int mt=0;mt<4;mt++){
      int4 vv = *(const int4*)&vloc[mt*16 + quad*4];
      int vls[4] = {vv.x, vv.y, vv.z, vv.w};
      #pragma unroll
      for(int p=0;p<2;p++){
        int colf = (2*w+p)*16 + n16;
        #pragma unroll
        for(int r=0;r<4;r++){
          int vl = vls[r];
          if(vl >= 0){
            float f  = sigmoidf_(c2[mt][p][r]   + shf[p]);
            float cc = softplusf_(c2[mt][p+2][r] + shc[p]);
            atomicAdd(&accs[vl][colf], f*cc);
          }
        }
      }
    }
  }
  __syncthreads();
  { // write 16 vertex rows, plain stores
    float4* dst = (float4*)(h_chem + (size_t)v0*H_DIM);
    const float4* src = (const float4*)accs;
    for(int i=t;i<16*H_DIM/4;i+=256) dst[i] = src[i];
  }
}

// ---------------- feat MLP via MFMA: 64 vertices/block -> out [V,128] f32
__global__ __launch_bounds__(256) void feat_mfma(
    const float* __restrict__ h_chem, const f16* __restrict__ h_geom,
    const f16* __restrict__ wf1f, const float* __restrict__ shf1,
    const f16* __restrict__ wf2f, const float* __restrict__ shf2,
    float* __restrict__ out)
{
  __shared__ f16 Af[64][200];   // row 400B (stagger 4 banks), K=192
  const int t = threadIdx.x, w = t>>6, lane = t&63, n16 = lane&15, quad = lane>>4;
  const int v0 = blockIdx.x*64;

  for(int i=t;i<64*128;i+=256){ int r=i>>7, k=i&127; Af[r][k] = (f16)h_chem[(size_t)(v0+r)*128 + k]; }
  for(int i=t;i<64*64;i+=256){ int r=i>>6, k=i&63; Af[r][128+k] = h_geom[(size_t)(v0+r)*64 + k]; }

  f16x8 B1[2][6];
  #pragma unroll
  for(int p=0;p<2;p++){
    int col = (2*w+p)*16 + n16;
    #pragma unroll
    for(int ks=0;ks<6;ks++)
      B1[p][ks] = *(const f16x8*)(wf1f + (size_t)col*192 + ks*32 + quad*8);
  }
  __syncthreads();

  f32x4 c1[4][2];
  #pragma unroll
  for(int mt=0;mt<4;mt++){ c1[mt][0]=(f32x4)(0.f); c1[mt][1]=(f32x4)(0.f); }
  #pragma unroll
  for(int ks=0;ks<6;ks++){
    f16x8 a[4];
    #pragma unroll
    for(int mt=0;mt<4;mt++)
      a[mt] = *(const f16x8*)(&Af[mt*16+n16][ks*32+quad*8]);
    #pragma unroll
    for(int mt=0;mt<4;mt++)
      #pragma unroll
      for(int p=0;p<2;p++) c1[mt][p] = MFMA16(a[mt], B1[p][ks], c1[mt][p]);
  }
  __syncthreads();   // all layer-1 reads done

  float s1v[2] = { shf1[(2*w+0)*16+n16], shf1[(2*w+1)*16+n16] };
  #pragma unroll
  for(int mt=0;mt<4;mt++)
    #pragma unroll
    for(int p=0;p<2;p++){
      int col = (2*w+p)*16 + n16;
      #pragma unroll
      for(int r=0;r<4;r++)
        Af[mt*16+quad*4+r][col] = (f16)siluf_(c1[mt][p][r] + s1v[p]);
    }
  __syncthreads();

  f16x8 B2[2][4];
  #pragma unroll
  for(int p=0;p<2;p++){
    int col = (2*w+p)*16 + n16;
    #pragma unroll
    for(int ks=0;ks<4;ks++)
      B2[p][ks] = *(const f16x8*)(wf2f + (size_t)col*128 + ks*32 + quad*8);
  }
  f32x4 c2[4][2];
  #pragma unroll
  for(int mt=0;mt<4;mt++){ c2[mt][0]=(f32x4)(0.f); c2[mt][1]=(f32x4)(0.f); }
  #pragma unroll
  for(int ks=0;ks<4;ks++){
    f16x8 a[4];
    #pragma unroll
    for(int mt=0;mt<4;mt++)
      a[mt] = *(const f16x8*)(&Af[mt*16+n16][ks*32+quad*8]);
    #pragma unroll
    for(int mt=0;mt<4;mt++)
      #pragma unroll
      for(int p=0;p<2;p++) c2[mt][p] = MFMA16(a[mt], B2[p][ks], c2[mt][p]);
  }
  float s2v[2] = { shf2[(2*w+0)*16+n16], shf2[(2*w+1)*16+n16] };
  #pragma unroll
  for(int mt=0;mt<4;mt++)
    #pragma unroll
    for(int p=0;p<2;p++){
      int col = (2*w+p)*16 + n16;
      #pragma unroll
      for(int r=0;r<4;r++)
        out[(size_t)(v0 + mt*16+quad*4+r)*128 + col] = c2[mt][p][r] + s2v[p];
    }
}

extern "C" void kernel_launch(void* const* d_in, const int* in_sizes, int n_in,
                              void* d_out, int out_size, void* d_ws, size_t ws_size,
                              hipStream_t stream) {
  const float* chem = (const float*)d_in[0];
  const float* geom = (const float*)d_in[1];
  const int*   vids = (const int*)d_in[2];
  const float* w1  = (const float*)d_in[3];
  const float* b1  = (const float*)d_in[4];
  const float* bn1 = (const float*)d_in[5];
  const float* w2  = (const float*)d_in[6];
  const float* b2  = (const float*)d_in[7];
  const float* bn2 = (const float*)d_in[8];
  const float* wg1 = (const float*)d_in[9];
  const float* bg1 = (const float*)d_in[10];
  const float* bng1= (const float*)d_in[11];
  const float* wg2 = (const float*)d_in[12];
  const float* bg2 = (const float*)d_in[13];
  const float* bng2= (const float*)d_in[14];
  const float* wf1 = (const float*)d_in[15];
  const float* bf1 = (const float*)d_in[16];
  const float* bnf1= (const float*)d_in[17];
  const float* wf2 = (const float*)d_in[18];
  const float* bf2 = (const float*)d_in[19];
  const float* bnf2= (const float*)d_in[20];

  char* ws = (char*)d_ws;
  float* h_chem      = (float*)(ws + 0);             // 33554432
  f16*   h_geom      = (f16*)  (ws + 33554432);      // 8388608
  int*   perm        = (int*)  (ws + 41943040);      // 4194304
  int*   counts      = (int*)  (ws + 46137344);      // 262144
  int*   offsets     = (int*)  (ws + 46399488);      // 262400 (65537 ints, padded)
  int*   offsets_wk  = (int*)  (ws + 46661888);      // 262144
  f16*   w1f         = (f16*)  (ws + 46924032);      // 16384
  f16*   w2f         = (f16*)  (ws + 46940416);      // 65536
  f16*   wg1f        = (f16*)  (ws + 47005952);      // 8192
  f16*   wg2f        = (f16*)  (ws + 47014144);      // 8192
  f16*   wf1f        = (f16*)  (ws + 47022336);      // 49152
  f16*   wf2f        = (f16*)  (ws + 47071488);      // 32768
  float* shift1      = (float*)(ws + 47104256);      // 512
  float* shift2      = (float*)(ws + 47104768);      // 1024
  float* shiftg1     = (float*)(ws + 47105792);      // 256
  float* shiftg2     = (float*)(ws + 47106048);      // 256
  float* shiftf1     = (float*)(ws + 47106304);      // 512
  float* shiftf2     = (float*)(ws + 47106816);      // 512
  float* out         = (float*)d_out;

  hipMemsetAsync(counts, 0, 65536*sizeof(int), stream);
  prep_kernel<<<dim3(128), dim3(256), 0, stream>>>(
      w1,b1,bn1, w2,b2,bn2, wg1,bg1,bng1, wg2,bg2,bng2, wf1,bf1,bnf1, wf2,bf2,bnf2,
      w1f,shift1, w2f,shift2, wg1f,shiftg1, wg2f,shiftg2, wf1f,shiftf1, wf2f,shiftf2);
  hist_kernel<<<dim3(1024), dim3(256), 0, stream>>>(vids, counts);
  scan_kernel<<<dim3(1), dim3(1024), 0, stream>>>(counts, offsets, offsets_wk);
  scatter_kernel<<<dim3(1024), dim3(256), 0, stream>>>(vids, offsets_wk, perm);
  geom_mfma<<<dim3(V_CNT/64), dim3(256), 0, stream>>>(geom, wg1f,shiftg1, wg2f,shiftg2, h_geom);
  chem_gather<<<dim3(V_CNT/16), dim3(256), 0, stream>>>(chem, perm, offsets, w1f,shift1, w2f,shift2, h_chem);
  feat_mfma<<<dim3(V_CNT/64), dim3(256), 0, stream>>>(h_chem, h_geom, wf1f,shiftf1, wf2f,shiftf2, out);
}